// Round 5
// baseline (3789.968 us; speedup 1.0000x reference)
//
#include <hip/hip_runtime.h>

typedef short bf16x8 __attribute__((ext_vector_type(8)));
typedef float f32x4 __attribute__((ext_vector_type(4)));

#define LOG2E 1.44269504088896340736f

__device__ __forceinline__ unsigned short f2bf(float x) {
    unsigned u = __builtin_bit_cast(unsigned, x);
    return (unsigned short)((u + 0x7fffu + ((u >> 16) & 1u)) >> 16);
}

// 512 blocks x 512 threads (2 blocks/CU). Block owns 16 batch rows; wave owns
// 16 hidden channels across all 4 gate strips. Persistent loop over 2048 steps.
// Round-2 structure exactly (8-slot ring, output GEMM after barrier, second
// barrier after it). Only delta vs round 2: merged-reciprocal tail --
//   r3 = rcp((1+yf)(1+yi)(1+yg)); sf = (1+yi)(1+yg)*r3; ig = (yg-1)(1+yf)*r3
// (5 exp2 + 2 rcp per hidden unit instead of 5 exp2 + 3 rcp).
__global__ __launch_bounds__(512, 4)
void lstm_persist(const float* __restrict__ zP, const float* __restrict__ condP,
                  const float* __restrict__ startP, const float* __restrict__ WihP,
                  const float* __restrict__ WhhP, const float* __restrict__ bihP,
                  const float* __restrict__ bhhP, const float* __restrict__ WoutP,
                  const float* __restrict__ boutP, float* __restrict__ outP)
{
    // h history ring: 8 slots x 16 rows x 128 hidden (bf16), XOR-swizzled rows
    __shared__ unsigned short hist[8 * 16 * 128];   // 32 KiB
    char* const lds = (char*)hist;

    const int tid  = threadIdx.x;
    const int wave = tid >> 6;
    const int lane = tid & 63;
    const int lo   = lane & 15;       // col within fragment
    const int gq   = lane >> 4;       // 0..3
    const int r0   = blockIdx.x * 16; // global batch-row base
    const int hid0 = wave * 16;       // this wave's hidden slice

    const float K2 = 2.0f * LOG2E;
    const float ss[4] = { -LOG2E, -LOG2E, 2.0f * LOG2E, -LOG2E };

    // ---- B fragments of W' = ss[s]*(W_hh + Wx @ W_out)  (bf16, registers) ----
    float wxs0[4], wxs1[4], bias[4];
    bf16x8 bfrag[4][4];
    #pragma unroll
    for (int s = 0; s < 4; ++s) {
        const int col = s * 128 + hid0 + lo;
        const float wx0 = WihP[col * 39 + 0];
        const float wx1 = WihP[col * 39 + 1];
        wxs0[s] = ss[s] * wx0;
        wxs1[s] = ss[s] * wx1;
        bias[s] = bihP[col] + bhhP[col];
        #pragma unroll
        for (int kt = 0; kt < 4; ++kt) {
            bf16x8 f;
            #pragma unroll
            for (int j = 0; j < 8; ++j) {
                const int k = kt * 32 + gq * 8 + j;
                const float w = WhhP[col * 128 + k]
                              + wx0 * WoutP[k] + wx1 * WoutP[128 + k];
                f[j] = (short)f2bf(ss[s] * w);
            }
            bfrag[s][kt] = f;
        }
    }

    // ---- W_out B-fragments for the batched output GEMM ----
    bf16x8 wof[4];
    #pragma unroll
    for (int kt = 0; kt < 4; ++kt) {
        bf16x8 f;
        #pragma unroll
        for (int j = 0; j < 8; ++j) {
            const int k = kt * 32 + gq * 8 + j;
            f[j] = (lo < 2) ? (short)f2bf(WoutP[lo * 128 + k]) : (short)0;
        }
        wof[kt] = f;
    }
    const float bo = (lo < 2) ? boutP[lo] : 0.0f;

    // ---- static projection into registers (C-fragment layout, pre-scaled) ----
    f32x4 sp[4];  // [strip], components = rr (row = gq*4+rr)
    #pragma unroll
    for (int s = 0; s < 4; ++s)
        #pragma unroll
        for (int rr = 0; rr < 4; ++rr)
            sp[s][rr] = bias[s];

    for (int j = 0; j < 32; ++j) {   // z part
        float w[4];
        #pragma unroll
        for (int s = 0; s < 4; ++s) w[s] = WihP[(s * 128 + hid0 + lo) * 39 + 2 + j];
        #pragma unroll
        for (int rr = 0; rr < 4; ++rr) {
            const int row = r0 + gq * 4 + rr;
            const float si = zP[row * 32 + j];
            #pragma unroll
            for (int s = 0; s < 4; ++s) sp[s][rr] += si * w[s];
        }
    }
    for (int j = 0; j < 4; ++j) {    // condition part
        float w[4];
        #pragma unroll
        for (int s = 0; s < 4; ++s) w[s] = WihP[(s * 128 + hid0 + lo) * 39 + 34 + j];
        #pragma unroll
        for (int rr = 0; rr < 4; ++rr) {
            const int row = r0 + gq * 4 + rr;
            const float si = condP[row * 4 + j];
            #pragma unroll
            for (int s = 0; s < 4; ++s) sp[s][rr] += si * w[s];
        }
    }
    #pragma unroll
    for (int s = 0; s < 4; ++s) {    // dt term + scale
        const float w = 0.05f * WihP[(s * 128 + hid0 + lo) * 39 + 38];
        #pragma unroll
        for (int rr = 0; rr < 4; ++rr) sp[s][rr] = ss[s] * (sp[s][rr] + w);
    }

    // ---- LDS offsets (swizzle: byte ^= (row&7)<<4) ----
    int wroff[4];
    #pragma unroll
    for (int rr = 0; rr < 4; ++rr) {
        const int row = gq * 4 + rr;
        wroff[rr] = (row * 256 + (hid0 + lo) * 2) ^ ((row & 7) << 4);
    }
    int rdoff[4];
    #pragma unroll
    for (int kt = 0; kt < 4; ++kt)
        rdoff[kt] = (lo * 256 + kt * 64 + gq * 16) ^ ((lo & 7) << 4);

    // ---- LSTM cell state ----
    f32x4 cst = f32x4{0.f, 0.f, 0.f, 0.f};

    // activation tail: scaled gates -> (h bf16 -> LDS), updates c
    auto tail = [&](f32x4 (&acc)[4], const int wbase) {
        float h[4];
        #pragma unroll
        for (int rr = 0; rr < 4; ++rr) {
            const float yi = __builtin_amdgcn_exp2f(__builtin_fminf(acc[0][rr], 40.f));
            const float yf = __builtin_amdgcn_exp2f(__builtin_fminf(acc[1][rr], 40.f));
            const float yg = __builtin_amdgcn_exp2f(__builtin_fminf(acc[2][rr], 40.f));
            const float yo = __builtin_amdgcn_exp2f(__builtin_fminf(acc[3][rr], 40.f));
            const float pf  = 1.0f + yf;
            const float pig = (1.0f + yi) * (1.0f + yg);
            const float r3  = __builtin_amdgcn_rcpf(pf * pig);
            const float sf  = pig * r3;                       // sigmoid(f)
            const float ig  = (yg - 1.0f) * pf * r3;          // sigmoid(i)*tanh(g)
            const float cn  = __builtin_fmaf(sf, cst[rr], ig);
            cst[rr] = cn;
            const float yc  = __builtin_amdgcn_exp2f(__builtin_fminf(cn * K2, 40.f));
            const float roc = __builtin_amdgcn_rcpf((1.0f + yo) * (1.0f + yc));
            h[rr] = (yc - 1.0f) * roc;                        // sigmoid(o)*tanh(c)
        }
        unsigned p01, p23;
        asm("v_cvt_pk_bf16_f32 %0, %1, %2" : "=v"(p01) : "v"(h[0]), "v"(h[1]));
        asm("v_cvt_pk_bf16_f32 %0, %1, %2" : "=v"(p23) : "v"(h[2]), "v"(h[3]));
        *(unsigned short*)(lds + wbase + wroff[0]) = (unsigned short)(p01 & 0xffffu);
        *(unsigned short*)(lds + wbase + wroff[1]) = (unsigned short)(p01 >> 16);
        *(unsigned short*)(lds + wbase + wroff[2]) = (unsigned short)(p23 & 0xffffu);
        *(unsigned short*)(lds + wbase + wroff[3]) = (unsigned short)(p23 >> 16);
    };

    // ---- step 0: gates = ss*(x_start@Wx.T) + SP (pure VALU, h0 = c0 = 0) ----
    {
        f32x4 acc0[4];
        #pragma unroll
        for (int s = 0; s < 4; ++s) acc0[s] = sp[s];
        #pragma unroll
        for (int rr = 0; rr < 4; ++rr) {
            const int row = r0 + gq * 4 + rr;
            const float x0 = startP[row * 2 + 0];
            const float x1 = startP[row * 2 + 1];
            #pragma unroll
            for (int s = 0; s < 4; ++s)
                acc0[s][rr] += x0 * wxs0[s] + x1 * wxs1[s];
        }
        tail(acc0, 0);   // slot 0
    }
    // fold bx = ss*(Wx@b_out) into sp for t >= 1
    #pragma unroll
    for (int s = 0; s < 4; ++s) {
        const float bx = wxs0[s] * boutP[0] + wxs1[s] * boutP[1];
        #pragma unroll
        for (int rr = 0; rr < 4; ++rr) sp[s][rr] += bx;
    }
    __syncthreads();

    // ---- main recurrence (round-2 structure) ----
    #pragma unroll 1
    for (int t = 1; t < 2048; ++t) {
        const int rbase = ((t - 1) & 7) * 4096;
        const int wbase = (t & 7) * 4096;

        bf16x8 af[4];
        #pragma unroll
        for (int kt = 0; kt < 4; ++kt)
            af[kt] = __builtin_bit_cast(bf16x8, *(const f32x4*)(lds + rbase + rdoff[kt]));

        f32x4 acc[4];
        #pragma unroll
        for (int s = 0; s < 4; ++s) {
            f32x4 a = sp[s];
            #pragma unroll
            for (int kt = 0; kt < 4; ++kt)
                a = __builtin_amdgcn_mfma_f32_16x16x32_bf16(af[kt], bfrag[s][kt], a, 0, 0, 0);
            acc[s] = a;
        }
        tail(acc, wbase);
        __syncthreads();

        // every 8 steps: batched output GEMM over the full history ring.
        // wave w handles timestep (t-7+w) = slot w, all 16 rows.
        if ((t & 7) == 7) {
            f32x4 xacc = f32x4{0.f, 0.f, 0.f, 0.f};
            #pragma unroll
            for (int kt = 0; kt < 4; ++kt) {
                const bf16x8 a = __builtin_bit_cast(bf16x8,
                    *(const f32x4*)(lds + wave * 4096 + rdoff[kt]));
                xacc = __builtin_amdgcn_mfma_f32_16x16x32_bf16(a, wof[kt], xacc, 0, 0, 0);
            }
            const int tg = t - 7 + wave;
            if (lo < 2) {
                #pragma unroll
                for (int rr = 0; rr < 4; ++rr) {
                    const int row = gq * 4 + rr;
                    outP[(size_t)(r0 + row) * 4096 + tg * 2 + lo] = xacc[rr] + bo;
                }
            }
            __syncthreads();
        }
    }
}

extern "C" void kernel_launch(void* const* d_in, const int* in_sizes, int n_in,
                              void* d_out, int out_size, void* d_ws, size_t ws_size,
                              hipStream_t stream) {
    const float* z    = (const float*)d_in[0];
    const float* cond = (const float*)d_in[1];
    const float* strt = (const float*)d_in[2];
    const float* Wih  = (const float*)d_in[3];
    const float* Whh  = (const float*)d_in[4];
    const float* bih  = (const float*)d_in[5];
    const float* bhh  = (const float*)d_in[6];
    const float* Wout = (const float*)d_in[7];
    const float* bout = (const float*)d_in[8];
    float* out = (float*)d_out;

    hipLaunchKernelGGL(lstm_persist, dim3(512), dim3(512), 0, stream,
                       z, cond, strt, Wih, Whh, bih, bhh, Wout, bout, out);
}

// Round 7
// 2902.582 us; speedup vs baseline: 1.3057x; 1.3057x over previous
//
#include <hip/hip_runtime.h>

typedef short bf16x8 __attribute__((ext_vector_type(8)));
typedef float f32x4 __attribute__((ext_vector_type(4)));

#define LOG2E 1.44269504088896340736f

__device__ __forceinline__ unsigned short f2bf(float x) {
    unsigned u = __builtin_bit_cast(unsigned, x);
    return (unsigned short)((u + 0x7fffu + ((u >> 16) & 1u)) >> 16);
}

// 256 blocks x 512 threads (1 block/CU). Block owns 32 batch rows as TWO
// independent 16-row groups (A,B) sharing weight registers; wave owns 16
// hidden channels across all 4 gate strips for both groups. Per step:
// MFMA-A, MFMA-B, tail-A, tail-B, barrier -- group B's independent chains
// overlap group A's transcendental latency chains within each wave.
// Tail math and LDS layout are byte-identical to the round-2 kernel.
__global__ __launch_bounds__(512, 2)
void lstm_persist(const float* __restrict__ zP, const float* __restrict__ condP,
                  const float* __restrict__ startP, const float* __restrict__ WihP,
                  const float* __restrict__ WhhP, const float* __restrict__ bihP,
                  const float* __restrict__ bhhP, const float* __restrict__ WoutP,
                  const float* __restrict__ boutP, float* __restrict__ outP)
{
    // two h history rings: 2 x (8 slots x 16 rows x 128 hidden) bf16, swizzled
    __shared__ unsigned short hist[2 * 8 * 16 * 128];   // 64 KiB
    char* const lds = (char*)hist;                      // group B at +32768

    const int tid  = threadIdx.x;
    const int wave = tid >> 6;
    const int lane = tid & 63;
    const int lo   = lane & 15;       // col within fragment
    const int gq   = lane >> 4;       // 0..3
    const int r0   = blockIdx.x * 32; // global batch-row base (A: +0, B: +16)
    const int hid0 = wave * 16;       // this wave's hidden slice

    const float K2 = 2.0f * LOG2E;
    const float ss[4] = { -LOG2E, -LOG2E, 2.0f * LOG2E, -LOG2E };

    // ---- B fragments of W' = ss[s]*(W_hh + Wx @ W_out)  (bf16, registers) ----
    float wxs0[4], wxs1[4], bias[4];
    bf16x8 bfrag[4][4];
    #pragma unroll
    for (int s = 0; s < 4; ++s) {
        const int col = s * 128 + hid0 + lo;
        const float wx0 = WihP[col * 39 + 0];
        const float wx1 = WihP[col * 39 + 1];
        wxs0[s] = ss[s] * wx0;
        wxs1[s] = ss[s] * wx1;
        bias[s] = bihP[col] + bhhP[col];
        #pragma unroll
        for (int kt = 0; kt < 4; ++kt) {
            bf16x8 f;
            #pragma unroll
            for (int j = 0; j < 8; ++j) {
                const int k = kt * 32 + gq * 8 + j;
                const float w = WhhP[col * 128 + k]
                              + wx0 * WoutP[k] + wx1 * WoutP[128 + k];
                f[j] = (short)f2bf(ss[s] * w);
            }
            bfrag[s][kt] = f;
        }
    }

    // ---- W_out B-fragments for the batched output GEMM ----
    bf16x8 wof[4];
    #pragma unroll
    for (int kt = 0; kt < 4; ++kt) {
        bf16x8 f;
        #pragma unroll
        for (int j = 0; j < 8; ++j) {
            const int k = kt * 32 + gq * 8 + j;
            f[j] = (lo < 2) ? (short)f2bf(WoutP[lo * 128 + k]) : (short)0;
        }
        wof[kt] = f;
    }
    const float bo = (lo < 2) ? boutP[lo] : 0.0f;

    // ---- static projection for both groups (C-fragment layout, pre-scaled) --
    f32x4 spA[4], spB[4];  // [strip], components = rr (row = grp + gq*4+rr)
    #pragma unroll
    for (int s = 0; s < 4; ++s)
        #pragma unroll
        for (int rr = 0; rr < 4; ++rr) { spA[s][rr] = bias[s]; spB[s][rr] = bias[s]; }

    for (int j = 0; j < 32; ++j) {   // z part
        float w[4];
        #pragma unroll
        for (int s = 0; s < 4; ++s) w[s] = WihP[(s * 128 + hid0 + lo) * 39 + 2 + j];
        #pragma unroll
        for (int rr = 0; rr < 4; ++rr) {
            const int rowA = r0 + gq * 4 + rr;
            const float sa = zP[rowA * 32 + j];
            const float sb = zP[(rowA + 16) * 32 + j];
            #pragma unroll
            for (int s = 0; s < 4; ++s) { spA[s][rr] += sa * w[s]; spB[s][rr] += sb * w[s]; }
        }
    }
    for (int j = 0; j < 4; ++j) {    // condition part
        float w[4];
        #pragma unroll
        for (int s = 0; s < 4; ++s) w[s] = WihP[(s * 128 + hid0 + lo) * 39 + 34 + j];
        #pragma unroll
        for (int rr = 0; rr < 4; ++rr) {
            const int rowA = r0 + gq * 4 + rr;
            const float sa = condP[rowA * 4 + j];
            const float sb = condP[(rowA + 16) * 4 + j];
            #pragma unroll
            for (int s = 0; s < 4; ++s) { spA[s][rr] += sa * w[s]; spB[s][rr] += sb * w[s]; }
        }
    }
    #pragma unroll
    for (int s = 0; s < 4; ++s) {    // dt term + scale
        const float w = 0.05f * WihP[(s * 128 + hid0 + lo) * 39 + 38];
        #pragma unroll
        for (int rr = 0; rr < 4; ++rr) {
            spA[s][rr] = ss[s] * (spA[s][rr] + w);
            spB[s][rr] = ss[s] * (spB[s][rr] + w);
        }
    }

    // ---- LDS offsets (swizzle: byte ^= (row&7)<<4) ----
    int wroff[4];
    #pragma unroll
    for (int rr = 0; rr < 4; ++rr) {
        const int row = gq * 4 + rr;
        wroff[rr] = (row * 256 + (hid0 + lo) * 2) ^ ((row & 7) << 4);
    }
    int rdoff[4];
    #pragma unroll
    for (int kt = 0; kt < 4; ++kt)
        rdoff[kt] = (lo * 256 + kt * 64 + gq * 16) ^ ((lo & 7) << 4);

    // ---- LSTM cell state (per group) ----
    f32x4 cstA = f32x4{0.f, 0.f, 0.f, 0.f};
    f32x4 cstB = f32x4{0.f, 0.f, 0.f, 0.f};

    // activation tail (round-2 math): scaled gates -> h bf16 -> LDS, updates c
    auto tail = [&](f32x4 (&acc)[4], f32x4& cst, const int wbyte) {
        float h[4];
        #pragma unroll
        for (int rr = 0; rr < 4; ++rr) {
            const float si = __builtin_amdgcn_rcpf(1.0f + __builtin_amdgcn_exp2f(acc[0][rr]));
            const float sf = __builtin_amdgcn_rcpf(1.0f + __builtin_amdgcn_exp2f(acc[1][rr]));
            const float rg = __builtin_amdgcn_rcpf(1.0f + __builtin_amdgcn_exp2f(acc[2][rr]));
            const float so = __builtin_amdgcn_rcpf(1.0f + __builtin_amdgcn_exp2f(acc[3][rr]));
            const float tg = __builtin_fmaf(rg, -2.0f, 1.0f);
            const float cn = __builtin_fmaf(sf, cst[rr], si * tg);
            cst[rr] = cn;
            const float rc = __builtin_amdgcn_rcpf(1.0f + __builtin_amdgcn_exp2f(cn * K2));
            const float tc = __builtin_fmaf(rc, -2.0f, 1.0f);
            h[rr] = so * tc;
        }
        unsigned p01, p23;
        asm("v_cvt_pk_bf16_f32 %0, %1, %2" : "=v"(p01) : "v"(h[0]), "v"(h[1]));
        asm("v_cvt_pk_bf16_f32 %0, %1, %2" : "=v"(p23) : "v"(h[2]), "v"(h[3]));
        *(unsigned short*)(lds + wbyte + wroff[0]) = (unsigned short)(p01 & 0xffffu);
        *(unsigned short*)(lds + wbyte + wroff[1]) = (unsigned short)(p01 >> 16);
        *(unsigned short*)(lds + wbyte + wroff[2]) = (unsigned short)(p23 & 0xffffu);
        *(unsigned short*)(lds + wbyte + wroff[3]) = (unsigned short)(p23 >> 16);
    };

    // ---- step 0 for both groups (pure VALU, h0 = c0 = 0) ----
    {
        f32x4 accA[4], accB[4];
        #pragma unroll
        for (int s = 0; s < 4; ++s) { accA[s] = spA[s]; accB[s] = spB[s]; }
        #pragma unroll
        for (int rr = 0; rr < 4; ++rr) {
            const int rowA = r0 + gq * 4 + rr;
            const float a0 = startP[rowA * 2 + 0];
            const float a1 = startP[rowA * 2 + 1];
            const float b0 = startP[(rowA + 16) * 2 + 0];
            const float b1 = startP[(rowA + 16) * 2 + 1];
            #pragma unroll
            for (int s = 0; s < 4; ++s) {
                accA[s][rr] += a0 * wxs0[s] + a1 * wxs1[s];
                accB[s][rr] += b0 * wxs0[s] + b1 * wxs1[s];
            }
        }
        tail(accA, cstA, 0);           // group A, slot 0
        tail(accB, cstB, 32768);       // group B, slot 0
    }
    // fold bx = ss*(Wx@b_out) into sp for t >= 1
    #pragma unroll
    for (int s = 0; s < 4; ++s) {
        const float bx = wxs0[s] * boutP[0] + wxs1[s] * boutP[1];
        #pragma unroll
        for (int rr = 0; rr < 4; ++rr) { spA[s][rr] += bx; spB[s][rr] += bx; }
    }
    __syncthreads();

    // ---- main recurrence ----
    #pragma unroll 1
    for (int t = 1; t < 2048; ++t) {
        const int rbase = ((t - 1) & 7) * 4096;
        const int wbase = (t & 7) * 4096;

        // group A: read + MFMA
        bf16x8 afA[4];
        #pragma unroll
        for (int kt = 0; kt < 4; ++kt)
            afA[kt] = __builtin_bit_cast(bf16x8, *(const f32x4*)(lds + rbase + rdoff[kt]));
        f32x4 accA[4];
        #pragma unroll
        for (int s = 0; s < 4; ++s) {
            f32x4 a = spA[s];
            #pragma unroll
            for (int kt = 0; kt < 4; ++kt)
                a = __builtin_amdgcn_mfma_f32_16x16x32_bf16(afA[kt], bfrag[s][kt], a, 0, 0, 0);
            accA[s] = a;
        }

        // group B: read + MFMA (independent of group A's tail)
        bf16x8 afB[4];
        #pragma unroll
        for (int kt = 0; kt < 4; ++kt)
            afB[kt] = __builtin_bit_cast(bf16x8, *(const f32x4*)(lds + 32768 + rbase + rdoff[kt]));
        f32x4 accB[4];
        #pragma unroll
        for (int s = 0; s < 4; ++s) {
            f32x4 a = spB[s];
            #pragma unroll
            for (int kt = 0; kt < 4; ++kt)
                a = __builtin_amdgcn_mfma_f32_16x16x32_bf16(afB[kt], bfrag[s][kt], a, 0, 0, 0);
            accB[s] = a;
        }

        tail(accA, cstA, wbase);
        tail(accB, cstB, 32768 + wbase);
        __syncthreads();

        // every 8 steps: batched output GEMM over each group's ring.
        // wave w handles timestep (t-7+w) = slot w, 16 rows per group.
        if ((t & 7) == 7) {
            f32x4 xa = f32x4{0.f, 0.f, 0.f, 0.f};
            f32x4 xb = f32x4{0.f, 0.f, 0.f, 0.f};
            #pragma unroll
            for (int kt = 0; kt < 4; ++kt) {
                const bf16x8 a = __builtin_bit_cast(bf16x8,
                    *(const f32x4*)(lds + wave * 4096 + rdoff[kt]));
                xa = __builtin_amdgcn_mfma_f32_16x16x32_bf16(a, wof[kt], xa, 0, 0, 0);
                const bf16x8 b = __builtin_bit_cast(bf16x8,
                    *(const f32x4*)(lds + 32768 + wave * 4096 + rdoff[kt]));
                xb = __builtin_amdgcn_mfma_f32_16x16x32_bf16(b, wof[kt], xb, 0, 0, 0);
            }
            const int tg = t - 7 + wave;
            if (lo < 2) {
                #pragma unroll
                for (int rr = 0; rr < 4; ++rr) {
                    const int row = gq * 4 + rr;
                    outP[(size_t)(r0 + row) * 4096 + tg * 2 + lo] = xa[rr] + bo;
                    outP[(size_t)(r0 + 16 + row) * 4096 + tg * 2 + lo] = xb[rr] + bo;
                }
            }
            __syncthreads();
        }
    }
}

extern "C" void kernel_launch(void* const* d_in, const int* in_sizes, int n_in,
                              void* d_out, int out_size, void* d_ws, size_t ws_size,
                              hipStream_t stream) {
    const float* z    = (const float*)d_in[0];
    const float* cond = (const float*)d_in[1];
    const float* strt = (const float*)d_in[2];
    const float* Wih  = (const float*)d_in[3];
    const float* Whh  = (const float*)d_in[4];
    const float* bih  = (const float*)d_in[5];
    const float* bhh  = (const float*)d_in[6];
    const float* Wout = (const float*)d_in[7];
    const float* bout = (const float*)d_in[8];
    float* out = (float*)d_out;

    hipLaunchKernelGGL(lstm_persist, dim3(256), dim3(512), 0, stream,
                       z, cond, strt, Wih, Whh, bih, bhh, Wout, bout, out);
}

// Round 8
// 2850.138 us; speedup vs baseline: 1.3297x; 1.0184x over previous
//
#include <hip/hip_runtime.h>

typedef short bf16x8 __attribute__((ext_vector_type(8)));
typedef float f32x4 __attribute__((ext_vector_type(4)));

#define LOG2E 1.44269504088896340736f

__device__ __forceinline__ unsigned short f2bf(float x) {
    unsigned u = __builtin_bit_cast(unsigned, x);
    return (unsigned short)((u + 0x7fffu + ((u >> 16) & 1u)) >> 16);
}

// 256 blocks x 512 threads (1 block/CU). Block owns 32 batch rows as TWO
// independent 16-row groups (A,B) sharing weight registers. Group B is skewed
// half a step behind A so every MFMA phase has the OTHER group's activation
// tail as independent VALU work in the same basic block:
//   phase1: MFMA-A(t) || tail-B(t-1)   -> barrier
//   phase2: MFMA-B(t) || tail-A(t) [+ output GEMM every 8 steps] -> barrier
// Rings are 16 deep so the output GEMM reads slots disjoint from concurrent
// writes (8 apart mod 16) -- no extra barrier. Tail math identical to r2/r7.
__global__ __launch_bounds__(512, 2)
void lstm_persist(const float* __restrict__ zP, const float* __restrict__ condP,
                  const float* __restrict__ startP, const float* __restrict__ WihP,
                  const float* __restrict__ WhhP, const float* __restrict__ bihP,
                  const float* __restrict__ bhhP, const float* __restrict__ WoutP,
                  const float* __restrict__ boutP, float* __restrict__ outP)
{
    // two h history rings: 2 x (16 slots x 16 rows x 128 hidden) bf16, swizzled
    __shared__ unsigned short hist[2 * 16 * 16 * 128];   // 128 KiB
    char* const lds = (char*)hist;                       // group B at +65536

    const int tid  = threadIdx.x;
    const int wave = tid >> 6;
    const int lane = tid & 63;
    const int lo   = lane & 15;       // col within fragment
    const int gq   = lane >> 4;       // 0..3
    const int r0   = blockIdx.x * 32; // global batch-row base (A: +0, B: +16)
    const int hid0 = wave * 16;       // this wave's hidden slice

    const float K2 = 2.0f * LOG2E;
    const float ss[4] = { -LOG2E, -LOG2E, 2.0f * LOG2E, -LOG2E };

    // ---- B fragments of W' = ss[s]*(W_hh + Wx @ W_out)  (bf16, registers) ----
    float wxs0[4], wxs1[4], bias[4];
    bf16x8 bfrag[4][4];
    #pragma unroll
    for (int s = 0; s < 4; ++s) {
        const int col = s * 128 + hid0 + lo;
        const float wx0 = WihP[col * 39 + 0];
        const float wx1 = WihP[col * 39 + 1];
        wxs0[s] = ss[s] * wx0;
        wxs1[s] = ss[s] * wx1;
        bias[s] = bihP[col] + bhhP[col];
        #pragma unroll
        for (int kt = 0; kt < 4; ++kt) {
            bf16x8 f;
            #pragma unroll
            for (int j = 0; j < 8; ++j) {
                const int k = kt * 32 + gq * 8 + j;
                const float w = WhhP[col * 128 + k]
                              + wx0 * WoutP[k] + wx1 * WoutP[128 + k];
                f[j] = (short)f2bf(ss[s] * w);
            }
            bfrag[s][kt] = f;
        }
    }

    // ---- W_out B-fragments for the batched output GEMM ----
    bf16x8 wof[4];
    #pragma unroll
    for (int kt = 0; kt < 4; ++kt) {
        bf16x8 f;
        #pragma unroll
        for (int j = 0; j < 8; ++j) {
            const int k = kt * 32 + gq * 8 + j;
            f[j] = (lo < 2) ? (short)f2bf(WoutP[lo * 128 + k]) : (short)0;
        }
        wof[kt] = f;
    }
    const float bo = (lo < 2) ? boutP[lo] : 0.0f;

    // ---- static projection for both groups (C-fragment layout, pre-scaled) --
    f32x4 spA[4], spB[4];  // [strip], components = rr (row = grp + gq*4+rr)
    #pragma unroll
    for (int s = 0; s < 4; ++s)
        #pragma unroll
        for (int rr = 0; rr < 4; ++rr) { spA[s][rr] = bias[s]; spB[s][rr] = bias[s]; }

    for (int j = 0; j < 32; ++j) {   // z part
        float w[4];
        #pragma unroll
        for (int s = 0; s < 4; ++s) w[s] = WihP[(s * 128 + hid0 + lo) * 39 + 2 + j];
        #pragma unroll
        for (int rr = 0; rr < 4; ++rr) {
            const int rowA = r0 + gq * 4 + rr;
            const float sa = zP[rowA * 32 + j];
            const float sb = zP[(rowA + 16) * 32 + j];
            #pragma unroll
            for (int s = 0; s < 4; ++s) { spA[s][rr] += sa * w[s]; spB[s][rr] += sb * w[s]; }
        }
    }
    for (int j = 0; j < 4; ++j) {    // condition part
        float w[4];
        #pragma unroll
        for (int s = 0; s < 4; ++s) w[s] = WihP[(s * 128 + hid0 + lo) * 39 + 34 + j];
        #pragma unroll
        for (int rr = 0; rr < 4; ++rr) {
            const int rowA = r0 + gq * 4 + rr;
            const float sa = condP[rowA * 4 + j];
            const float sb = condP[(rowA + 16) * 4 + j];
            #pragma unroll
            for (int s = 0; s < 4; ++s) { spA[s][rr] += sa * w[s]; spB[s][rr] += sb * w[s]; }
        }
    }
    #pragma unroll
    for (int s = 0; s < 4; ++s) {    // dt term + scale
        const float w = 0.05f * WihP[(s * 128 + hid0 + lo) * 39 + 38];
        #pragma unroll
        for (int rr = 0; rr < 4; ++rr) {
            spA[s][rr] = ss[s] * (spA[s][rr] + w);
            spB[s][rr] = ss[s] * (spB[s][rr] + w);
        }
    }

    // ---- LDS offsets (swizzle: byte ^= (row&7)<<4) ----
    int wroff[4];
    #pragma unroll
    for (int rr = 0; rr < 4; ++rr) {
        const int row = gq * 4 + rr;
        wroff[rr] = (row * 256 + (hid0 + lo) * 2) ^ ((row & 7) << 4);
    }
    int rdoff[4];
    #pragma unroll
    for (int kt = 0; kt < 4; ++kt)
        rdoff[kt] = (lo * 256 + kt * 64 + gq * 16) ^ ((lo & 7) << 4);

    // ---- LSTM cell state (per group) + pipelined gate accumulators ----
    f32x4 cstA = f32x4{0.f, 0.f, 0.f, 0.f};
    f32x4 cstB = f32x4{0.f, 0.f, 0.f, 0.f};
    f32x4 accA[4], accB[4];

    // activation tail (round-2 math): scaled gates -> h bf16 -> LDS, updates c
    auto tail = [&](f32x4 (&acc)[4], f32x4& cst, const int wbyte) {
        float h[4];
        #pragma unroll
        for (int rr = 0; rr < 4; ++rr) {
            const float si = __builtin_amdgcn_rcpf(1.0f + __builtin_amdgcn_exp2f(acc[0][rr]));
            const float sf = __builtin_amdgcn_rcpf(1.0f + __builtin_amdgcn_exp2f(acc[1][rr]));
            const float rg = __builtin_amdgcn_rcpf(1.0f + __builtin_amdgcn_exp2f(acc[2][rr]));
            const float so = __builtin_amdgcn_rcpf(1.0f + __builtin_amdgcn_exp2f(acc[3][rr]));
            const float tg = __builtin_fmaf(rg, -2.0f, 1.0f);
            const float cn = __builtin_fmaf(sf, cst[rr], si * tg);
            cst[rr] = cn;
            const float rc = __builtin_amdgcn_rcpf(1.0f + __builtin_amdgcn_exp2f(cn * K2));
            const float tc = __builtin_fmaf(rc, -2.0f, 1.0f);
            h[rr] = so * tc;
        }
        unsigned p01, p23;
        asm("v_cvt_pk_bf16_f32 %0, %1, %2" : "=v"(p01) : "v"(h[0]), "v"(h[1]));
        asm("v_cvt_pk_bf16_f32 %0, %1, %2" : "=v"(p23) : "v"(h[2]), "v"(h[3]));
        *(unsigned short*)(lds + wbyte + wroff[0]) = (unsigned short)(p01 & 0xffffu);
        *(unsigned short*)(lds + wbyte + wroff[1]) = (unsigned short)(p01 >> 16);
        *(unsigned short*)(lds + wbyte + wroff[2]) = (unsigned short)(p23 & 0xffffu);
        *(unsigned short*)(lds + wbyte + wroff[3]) = (unsigned short)(p23 >> 16);
    };

    // batched output GEMM for steps tb..tb+7 (slots (tb&15)..(tb&15)+7,
    // both groups); wave w handles step tb+w. Reads are 8 slots apart (mod 16)
    // from any concurrent tail write -> no barrier needed around it.
    auto outg = [&](const int tb) {
        const int sbase = ((tb & 15) + wave) * 4096;
        f32x4 xa = f32x4{0.f, 0.f, 0.f, 0.f};
        f32x4 xb = f32x4{0.f, 0.f, 0.f, 0.f};
        #pragma unroll
        for (int kt = 0; kt < 4; ++kt) {
            const bf16x8 a = __builtin_bit_cast(bf16x8,
                *(const f32x4*)(lds + sbase + rdoff[kt]));
            xa = __builtin_amdgcn_mfma_f32_16x16x32_bf16(a, wof[kt], xa, 0, 0, 0);
            const bf16x8 b = __builtin_bit_cast(bf16x8,
                *(const f32x4*)(lds + 65536 + sbase + rdoff[kt]));
            xb = __builtin_amdgcn_mfma_f32_16x16x32_bf16(b, wof[kt], xb, 0, 0, 0);
        }
        const int tg = tb + wave;
        if (lo < 2) {
            #pragma unroll
            for (int rr = 0; rr < 4; ++rr) {
                const int row = gq * 4 + rr;
                outP[(size_t)(r0 + row) * 4096 + tg * 2 + lo] = xa[rr] + bo;
                outP[(size_t)(r0 + 16 + row) * 4096 + tg * 2 + lo] = xb[rr] + bo;
            }
        }
    };

    // ---- step 0 for both groups (pure VALU, h0 = c0 = 0) ----
    {
        f32x4 accA0[4];
        #pragma unroll
        for (int s = 0; s < 4; ++s) { accA0[s] = spA[s]; accB[s] = spB[s]; }
        #pragma unroll
        for (int rr = 0; rr < 4; ++rr) {
            const int rowA = r0 + gq * 4 + rr;
            const float a0 = startP[rowA * 2 + 0];
            const float a1 = startP[rowA * 2 + 1];
            const float b0 = startP[(rowA + 16) * 2 + 0];
            const float b1 = startP[(rowA + 16) * 2 + 1];
            #pragma unroll
            for (int s = 0; s < 4; ++s) {
                accA0[s][rr] += a0 * wxs0[s] + a1 * wxs1[s];
                accB[s][rr]  += b0 * wxs0[s] + b1 * wxs1[s];
            }
        }
        tail(accA0, cstA, 0);   // group A, slot 0; accB(0) stays in registers
    }
    // fold bx = ss*(Wx@b_out) into sp for t >= 1
    #pragma unroll
    for (int s = 0; s < 4; ++s) {
        const float bx = wxs0[s] * boutP[0] + wxs1[s] * boutP[1];
        #pragma unroll
        for (int rr = 0; rr < 4; ++rr) { spA[s][rr] += bx; spB[s][rr] += bx; }
    }
    __syncthreads();

    // ---- main recurrence: two skewed phases per step ----
    #pragma unroll 1
    for (int t = 1; t < 2048; ++t) {
        const int rb = ((t - 1) & 15) * 4096;

        // phase 1: MFMA-A(t) from h_A(t-1)  ||  tail-B(t-1) (VALU)
        bf16x8 afA[4];
        #pragma unroll
        for (int kt = 0; kt < 4; ++kt)
            afA[kt] = __builtin_bit_cast(bf16x8, *(const f32x4*)(lds + rb + rdoff[kt]));
        #pragma unroll
        for (int s = 0; s < 4; ++s) {
            f32x4 a = spA[s];
            #pragma unroll
            for (int kt = 0; kt < 4; ++kt)
                a = __builtin_amdgcn_mfma_f32_16x16x32_bf16(afA[kt], bfrag[s][kt], a, 0, 0, 0);
            accA[s] = a;
        }
        tail(accB, cstB, 65536 + rb);          // writes h_B(t-1)
        __syncthreads();

        // phase 2: MFMA-B(t) from h_B(t-1)  ||  tail-A(t) (VALU) [+ outg]
        bf16x8 afB[4];
        #pragma unroll
        for (int kt = 0; kt < 4; ++kt)
            afB[kt] = __builtin_bit_cast(bf16x8, *(const f32x4*)(lds + 65536 + rb + rdoff[kt]));
        #pragma unroll
        for (int s = 0; s < 4; ++s) {
            f32x4 a = spB[s];
            #pragma unroll
            for (int kt = 0; kt < 4; ++kt)
                a = __builtin_amdgcn_mfma_f32_16x16x32_bf16(afB[kt], bfrag[s][kt], a, 0, 0, 0);
            accB[s] = a;
        }
        tail(accA, cstA, (t & 15) * 4096);     // writes h_A(t)
        if ((t & 7) == 0) outg(t - 8);         // steps t-8..t-1, both groups
        __syncthreads();
    }

    // ---- epilogue: finish group B's step 2047, then last output batch ----
    tail(accB, cstB, 65536 + 15 * 4096);       // h_B(2047), slot 15
    __syncthreads();
    outg(2040);                                // steps 2040..2047 (slots 8..15)
}

extern "C" void kernel_launch(void* const* d_in, const int* in_sizes, int n_in,
                              void* d_out, int out_size, void* d_ws, size_t ws_size,
                              hipStream_t stream) {
    const float* z    = (const float*)d_in[0];
    const float* cond = (const float*)d_in[1];
    const float* strt = (const float*)d_in[2];
    const float* Wih  = (const float*)d_in[3];
    const float* Whh  = (const float*)d_in[4];
    const float* bih  = (const float*)d_in[5];
    const float* bhh  = (const float*)d_in[6];
    const float* Wout = (const float*)d_in[7];
    const float* bout = (const float*)d_in[8];
    float* out = (float*)d_out;

    hipLaunchKernelGGL(lstm_persist, dim3(256), dim3(512), 0, stream,
                       z, cond, strt, Wih, Whh, bih, bhh, Wout, bout, out);
}